// Round 7
// baseline (116.522 us; speedup 1.0000x reference)
//
#include <hip/hip_runtime.h>
#include <math.h>

// QLSTM, single-kernel exact-polynomial formulation, 32 lanes/element,
// TWO interleaved element-chains per lane (4 elements/wave, 256 blocks).
// The 81 polynomial coefficients are element-independent -> shared by both
// chains; the second chain's instructions fill the first chain's latency
// bubbles (the kernel is chain-latency-bound at 0.25 waves/SIMD).
// xw staged in [elem][wire][t]-major LDS (stride 68: 16B-aligned, 2-way
// bank aliasing only) -> one ds_read_b128 per 4 steps per chain,
// double-buffered in registers, off the critical chain.

#define NQ 4
#define NL 2
#define BB 1024
#define TT 64
#define FF 32
#define HH 8

typedef float v2f __attribute__((ext_vector_type(2)));
typedef unsigned uv2 __attribute__((ext_vector_type(2)));
#define FMA2(a, b, c) __builtin_elementwise_fma((a), (b), (c))

// ---- register statevector circuit macros (verified rounds 1-6) -----------
#define RX_W(wv, cc, ss) do {                                   \
    const int str_ = 8 >> (wv);                                 \
    _Pragma("unroll")                                           \
    for (int lo_ = 0; lo_ < 16; ++lo_) {                        \
      if ((lo_ & str_) == 0) {                                  \
        const int hi_ = lo_ | str_;                             \
        float a0r = ar[lo_], a0i = ai[lo_];                     \
        float a1r = ar[hi_], a1i = ai[hi_];                     \
        ar[lo_] = fmaf((cc), a0r,  (ss)*a1i);                   \
        ai[lo_] = fmaf((cc), a0i, -(ss)*a1r);                   \
        ar[hi_] = fmaf((cc), a1r,  (ss)*a0i);                   \
        ai[hi_] = fmaf((cc), a1i, -(ss)*a0r);                   \
      }                                                         \
    }                                                           \
} while (0)

#define CNOT_W(cw, tw) do {                                     \
    const int cb_ = 1 << (3-(cw));                              \
    const int tb_ = 1 << (3-(tw));                              \
    _Pragma("unroll")                                           \
    for (int ix_ = 0; ix_ < 16; ++ix_) {                        \
      if ((ix_ & cb_) && !(ix_ & tb_)) {                        \
        const int jx_ = ix_ | tb_;                              \
        float tr_ = ar[ix_]; ar[ix_] = ar[jx_]; ar[jx_] = tr_;  \
        float ti_ = ai[ix_]; ai[ix_] = ai[jx_]; ai[jx_] = ti_;  \
      }                                                         \
    }                                                           \
} while (0)

#define QUAD_BCAST(x, CTRL) \
    __int_as_float(__builtin_amdgcn_mov_dpp(__float_as_int(x), (CTRL), 0xf, 0xf, true))
#define ROW_ROR(x, N) \
    __int_as_float(__builtin_amdgcn_mov_dpp(__float_as_int(x), 0x120 + (N), 0xf, 0xf, true))
#define SWZ_X16(x) \
    __int_as_float(__builtin_amdgcn_ds_swizzle(__float_as_int(x), 0x401F))

#if __has_builtin(__builtin_amdgcn_permlane16_swap)
__device__ __forceinline__ float permx16(float s, int lane) {
    uv2 r = __builtin_amdgcn_permlane16_swap(__builtin_bit_cast(unsigned, s),
                                             __builtin_bit_cast(unsigned, s),
                                             false, false);
    unsigned pick = (lane & 16) ? r.x : r.y;
    return __builtin_bit_cast(float, pick);
}
#else
__device__ __forceinline__ float permx16(float s, int lane) {
    (void)lane;
    return SWZ_X16(s);
}
#endif

#define TPASS(ST) do {                                                       \
    for (int i_ = threadIdx.x; i_ < 432; i_ += 64) {                         \
      int gw_ = i_ / 27; int r_ = i_ - gw_*27;                               \
      int hi_ = r_ / (ST); int lo_ = r_ - hi_*(ST);                          \
      float* row_ = sC + gw_*84; int p0_ = hi_*3*(ST) + lo_;                 \
      float f0_ = row_[p0_], f1_ = row_[p0_+(ST)], f2_ = row_[p0_+2*(ST)];   \
      row_[p0_]          = (f0_ + f1_ + f2_) * 0.3333333333333333f;          \
      row_[p0_+(ST)]     = (2.0f*f0_ - f1_ - f2_) * 0.3333333333333333f;     \
      row_[p0_+2*(ST)]   = (f1_ - f2_) * 0.5773502691896258f;                \
    }                                                                        \
    __syncthreads();                                                         \
} while (0)

// c3 accessor over packed pairs (k compile-time constant after unroll)
#define C3V(k) ((k) == 26 ? c3t : (((k) & 1) ? cp[(k) >> 1].y : cp[(k) >> 1].x))

// one full timestep for one element-chain; uses lane-constant
// wh,inS,outS,outB,E0,E1,E2,e0s,e1s,e2s,lane from enclosing scope.
#define STEP(xwv, cc, hh) do {                                               \
    float p_ = (hh) * wh;                                                    \
    float s_ = p_ + ROW_ROR(p_, 4);                                          \
    s_ = s_ + ROW_ROR(s_, 8);                                                \
    const float y_ = (xwv) + s_ + permx16(s_, lane);                         \
    const float u_ = __cosf(y_), vv_ = __sinf(y_);                           \
    const float u0_ = QUAD_BCAST(u_, 0x00), u1_ = QUAD_BCAST(u_, 0x55);      \
    const float u2_ = QUAD_BCAST(u_, 0xAA), u3_ = QUAD_BCAST(u_, 0xFF);      \
    const float v0_ = QUAD_BCAST(vv_, 0x00), v1_ = QUAD_BCAST(vv_, 0x55);    \
    const float v2_ = QUAD_BCAST(vv_, 0xAA), v3_ = QUAD_BCAST(vv_, 0xFF);    \
    const v2f u3p_ = {u3_, u3_}, v3p_ = {v3_, v3_};                          \
    v2f cp[14];                                                              \
    _Pragma("unroll")                                                        \
    for (int i_ = 0; i_ < 13; ++i_)                                          \
        cp[i_] = FMA2(u3p_, E1[i_], FMA2(v3p_, E2[i_], E0[i_]));             \
    const float c3t = fmaf(u3_, e1s, fmaf(v3_, e2s, e0s));                   \
    float c2v[9];                                                            \
    _Pragma("unroll")                                                        \
    for (int i_ = 0; i_ < 9; ++i_)                                           \
        c2v[i_] = fmaf(u2_, C3V(3*i_+1), fmaf(v2_, C3V(3*i_+2), C3V(3*i_))); \
    const float c1a_ = fmaf(u1_, c2v[1], fmaf(v1_, c2v[2], c2v[0]));         \
    const float c1b_ = fmaf(u1_, c2v[4], fmaf(v1_, c2v[5], c2v[3]));         \
    const float c1c_ = fmaf(u1_, c2v[7], fmaf(v1_, c2v[8], c2v[6]));         \
    const float a_ = fmaf(u0_, c1b_, fmaf(v0_, c1c_, c1a_));                 \
    const float sg_ = __builtin_amdgcn_rcpf(1.0f + __expf(-inS * a_));       \
    const float act_ = fmaf(sg_, outS, outB);                                \
    const float fv_ = QUAD_BCAST(act_, 0x00), iv_ = QUAD_BCAST(act_, 0x55);  \
    const float gv_ = QUAD_BCAST(act_, 0xAA), ov_ = QUAD_BCAST(act_, 0xFF);  \
    (cc) = fmaf(fv_, (cc), iv_ * gv_);                                       \
    const float th_ = fmaf(2.0f,                                             \
        __builtin_amdgcn_rcpf(1.0f + __expf(-2.0f * (cc))), -1.0f);          \
    (hh) = ov_ * th_;                                                        \
} while (0)

#define XSTRIDE 68   // floats; 272B: 16B-aligned rows, 2-way bank aliasing only

__global__ __launch_bounds__(64, 1)
void qlstm2x_kernel(const float* __restrict__ x,
                    const float* __restrict__ w_in,
                    const float* __restrict__ b_in,
                    const float* __restrict__ w_out,
                    const float* __restrict__ b_out,
                    const float* __restrict__ wq_f,
                    const float* __restrict__ wq_i,
                    const float* __restrict__ wq_u,
                    const float* __restrict__ wq_o,
                    const float* __restrict__ w_fc,
                    const float* __restrict__ b_fc,
                    float* __restrict__ out) {
    __shared__ float sC[16 * 84];                       // [g*4+wire][coeff]
    __shared__ __align__(16) float sXW[16 * XSTRIDE];   // [(ee*4+w)][t]

    const int lane = threadIdx.x;
    const int w    = lane & 3;          // gate id AND wire id for this lane
    const int j    = (lane >> 2) & 7;   // hidden unit owned by this lane
    const int e    = lane >> 5;         // half-wave: element pair selector

    // ---------------- P1: xw[(ee,w)][t] = b_in[w] + x[elem,t,:].w_in[w,8:] --
    {
        const float b0 = b_in[0], b1 = b_in[1], b2 = b_in[2], b3 = b_in[3];
        #pragma unroll
        for (int r = 0; r < 16; ++r) {
            int slot = lane + 64 * r;          // 0..1023 = ee(2) t(6) w(2)
            int ee = slot >> 8;
            int tt = (slot >> 2) & 63;
            int ww = slot & 3;
            const float* xr = x + ((size_t)(blockIdx.x * 4 + ee) * TT + tt) * FF;
            float bb = (ww == 0) ? b0 : (ww == 1) ? b1 : (ww == 2) ? b2 : b3;
            const float* wrow = w_in + ww * 40 + 8;
            float acc0 = bb, acc1 = 0.0f;
            #pragma unroll
            for (int k = 0; k < 8; k += 2) {
                float4 xa = *reinterpret_cast<const float4*>(xr + 4 * k);
                float4 xb = *reinterpret_cast<const float4*>(xr + 4 * k + 4);
                acc0 = fmaf(xa.x, wrow[4*k+0],
                       fmaf(xa.y, wrow[4*k+1],
                       fmaf(xa.z, wrow[4*k+2],
                       fmaf(xa.w, wrow[4*k+3], acc0))));
                acc1 = fmaf(xb.x, wrow[4*k+4],
                       fmaf(xb.y, wrow[4*k+5],
                       fmaf(xb.z, wrow[4*k+6],
                       fmaf(xb.w, wrow[4*k+7], acc1))));
            }
            sXW[(ee * 4 + ww) * XSTRIDE + tt] = acc0 + acc1;
        }
    }

    // ---------------- P2: simulate circuit at 81 constant grid points ------
    for (int sidx = lane; sidx < 324; sidx += 64) {
        int g = sidx / 81;
        int p = sidx - g * 81;
        int t0 = p / 27; int rem = p - t0 * 27;
        int t1 = rem / 9; rem -= t1 * 9;
        int t2 = rem / 3; int t3 = rem - t2 * 3;

        const float s3h = 0.8660254037844386f;
        float c0 = (t0 == 0) ? 1.0f : 0.5f;
        float s0 = (t0 == 0) ? 0.0f : ((t0 == 1) ? s3h : -s3h);
        float c1 = (t1 == 0) ? 1.0f : 0.5f;
        float s1 = (t1 == 0) ? 0.0f : ((t1 == 1) ? s3h : -s3h);
        float c2 = (t2 == 0) ? 1.0f : 0.5f;
        float s2 = (t2 == 0) ? 0.0f : ((t2 == 1) ? s3h : -s3h);
        float c3v = (t3 == 0) ? 1.0f : 0.5f;
        float s3v = (t3 == 0) ? 0.0f : ((t3 == 1) ? s3h : -s3h);

        const float* wq = (g == 0) ? wq_f : (g == 1) ? wq_i : (g == 2) ? wq_u : wq_o;
        float lc[NL * NQ], ls[NL * NQ];
        #pragma unroll
        for (int a = 0; a < NL * NQ; ++a) {
            float ang = wq[a] * 0.5f;
            lc[a] = __cosf(ang);
            ls[a] = __sinf(ang);
        }

        float m01[4], m23[4];
        m01[0] = c0 * c1;  m01[1] = c0 * s1;  m01[2] = s0 * c1;  m01[3] = s0 * s1;
        m23[0] = c2 * c3v; m23[1] = c2 * s3v; m23[2] = s2 * c3v; m23[3] = s2 * s3v;
        float ar[16], ai[16];
        #pragma unroll
        for (int b0 = 0; b0 < 2; ++b0)
        #pragma unroll
        for (int b1 = 0; b1 < 2; ++b1)
        #pragma unroll
        for (int b2 = 0; b2 < 2; ++b2)
        #pragma unroll
        for (int b3 = 0; b3 < 2; ++b3) {
            const int idx = (b0 << 3) | (b1 << 2) | (b2 << 1) | b3;
            const int pc  = (b0 + b1 + b2 + b3) & 3;
            float m = m01[(b0 << 1) | b1] * m23[(b2 << 1) | b3];
            float re, im;
            if (pc == 0)      { re =  m;   im = 0.0f; }
            else if (pc == 1) { re = 0.0f; im = -m;   }
            else if (pc == 2) { re = -m;   im = 0.0f; }
            else              { re = 0.0f; im =  m;   }
            ar[idx] = re; ai[idx] = im;
        }

        #pragma unroll
        for (int l = 0; l < NL; ++l) {
            RX_W(0, lc[l*4+0], ls[l*4+0]);
            RX_W(1, lc[l*4+1], ls[l*4+1]);
            RX_W(2, lc[l*4+2], ls[l*4+2]);
            RX_W(3, lc[l*4+3], ls[l*4+3]);
            CNOT_W(0, 1); CNOT_W(1, 2); CNOT_W(2, 3); CNOT_W(3, 0);
        }

        float e0 = 0.f, e1 = 0.f, e2 = 0.f, e3 = 0.f;
        #pragma unroll
        for (int idx = 0; idx < 16; ++idx) {
            float pv = fmaf(ar[idx], ar[idx], ai[idx] * ai[idx]);
            e0 += (idx & 8) ? -pv : pv;
            e1 += (idx & 4) ? -pv : pv;
            e2 += (idx & 2) ? -pv : pv;
            e3 += (idx & 1) ? -pv : pv;
        }
        sC[(g * 4 + 0) * 84 + p] = e0;
        sC[(g * 4 + 1) * 84 + p] = e1;
        sC[(g * 4 + 2) * 84 + p] = e2;
        sC[(g * 4 + 3) * 84 + p] = e3;
    }
    __syncthreads();

    // ---------------- P3: inverse transform (values -> coefficients) -------
    TPASS(27); TPASS(9); TPASS(3); TPASS(1);

    // ---------------- P4: fold w_out/b_out -> per-lane packed coefficients --
    v2f E0[13], E1[13], E2[13];
    float e0s, e1s, e2s;
    {
        const float x0 = w_out[j * 4 + 0], x1 = w_out[j * 4 + 1];
        const float x2 = w_out[j * 4 + 2], x3 = w_out[j * 4 + 3];
        const float bo = b_out[j];
        const float* r0 = sC + (w * 4 + 0) * 84;
        const float* r1 = sC + (w * 4 + 1) * 84;
        const float* r2 = sC + (w * 4 + 2) * 84;
        const float* r3 = sC + (w * 4 + 3) * 84;
        #define DVAL(i) (fmaf(x0, r0[(i)], fmaf(x1, r1[(i)], fmaf(x2, r2[(i)], x3 * r3[(i)]))) \
                         + (((i) == 0) ? bo : 0.0f))
        #pragma unroll
        for (int p = 0; p < 13; ++p) {
            E0[p] = v2f{DVAL(6*p + 0), DVAL(6*p + 3)};
            E1[p] = v2f{DVAL(6*p + 1), DVAL(6*p + 4)};
            E2[p] = v2f{DVAL(6*p + 2), DVAL(6*p + 5)};
        }
        e0s = DVAL(78); e1s = DVAL(79); e2s = DVAL(80);
        #undef DVAL
    }
    #pragma unroll
    for (int i = 0; i < 13; ++i)
        asm volatile("" : "+v"(E0[i]), "+v"(E1[i]), "+v"(E2[i]));
    asm volatile("" : "+v"(e0s), "+v"(e1s), "+v"(e2s));

    // ---------------- main recurrence: 2 interleaved element-chains --------
    const float wh  = w_in[w * 40 + j];
    const float wfc = w_fc[j];
    const bool  isG  = (w == 2);
    const float inS  = isG ? 2.0f : 1.0f;
    const float outS = isG ? 2.0f : 1.0f;
    const float outB = isG ? -1.0f : 0.0f;

    const float* pA = sXW + ((e * 2 + 0) * 4 + w) * XSTRIDE;
    const float* pB = sXW + ((e * 2 + 1) * 4 + w) * XSTRIDE;

    float ccA = 0.0f, hhA = 0.0f, ccB = 0.0f, hhB = 0.0f;
    float4 xqA = *reinterpret_cast<const float4*>(pA);
    float4 xqB = *reinterpret_cast<const float4*>(pB);

    #pragma unroll 1
    for (int g4 = 0; g4 < 16; ++g4) {
        const int nx = (g4 < 15) ? (g4 + 1) * 4 : 60;   // clamp (discarded)
        float4 xqAn = *reinterpret_cast<const float4*>(pA + nx);
        float4 xqBn = *reinterpret_cast<const float4*>(pB + nx);

        STEP(xqA.x, ccA, hhA); STEP(xqB.x, ccB, hhB);
        STEP(xqA.y, ccA, hhA); STEP(xqB.y, ccB, hhB);
        STEP(xqA.z, ccA, hhA); STEP(xqB.z, ccB, hhB);
        STEP(xqA.w, ccA, hhA); STEP(xqB.w, ccB, hhB);

        xqA = xqAn; xqB = xqBn;
    }

    // ---------------- epilogue: out = h.w_fc + b_fc ------------------------
    float pfA = hhA * wfc;
    float sfA = pfA + ROW_ROR(pfA, 4);
    sfA = sfA + ROW_ROR(sfA, 8);
    sfA = sfA + permx16(sfA, lane);
    float pfB = hhB * wfc;
    float sfB = pfB + ROW_ROR(pfB, 4);
    sfB = sfB + ROW_ROR(sfB, 8);
    sfB = sfB + permx16(sfB, lane);
    if ((lane & 31) == 0) {
        const int base = blockIdx.x * 4 + e * 2;
        out[base]     = sfA + b_fc[0];
        out[base + 1] = sfB + b_fc[0];
    }
}

extern "C" void kernel_launch(void* const* d_in, const int* in_sizes, int n_in,
                              void* d_out, int out_size, void* d_ws, size_t ws_size,
                              hipStream_t stream) {
    const float* x     = (const float*)d_in[0];
    const float* w_in  = (const float*)d_in[1];
    const float* b_in  = (const float*)d_in[2];
    const float* w_out = (const float*)d_in[3];
    const float* b_out = (const float*)d_in[4];
    const float* wq_f  = (const float*)d_in[5];
    const float* wq_i  = (const float*)d_in[6];
    const float* wq_u  = (const float*)d_in[7];
    const float* wq_o  = (const float*)d_in[8];
    const float* w_fc  = (const float*)d_in[9];
    const float* b_fc  = (const float*)d_in[10];
    float* out = (float*)d_out;
    (void)in_sizes; (void)n_in; (void)out_size; (void)d_ws; (void)ws_size;

    qlstm2x_kernel<<<BB / 4, 64, 0, stream>>>(x, w_in, b_in, w_out, b_out,
                                              wq_f, wq_i, wq_u, wq_o,
                                              w_fc, b_fc, out);
}

// Round 9
// 88.956 us; speedup vs baseline: 1.3099x; 1.3099x over previous
//
#include <hip/hip_runtime.h>
#include <math.h>

// QLSTM via exact 12-string Heisenberg reduction of the 4-qubit 2-layer VQC.
// Propagating Z_w back through (RX layer, CNOT ring 01,12,23,30) x2 with FULL
// X-cancellation tracking (C(Y_c ox X_t)C = Y_c, the path round 8 missed):
//   t_q = cos(y_q+phi_q), r_q = sin(y_q+phi_q)   [phi = layer-0 angles]
//   c_q = cos(psi_q),     s_q = sin(psi_q)       [psi = layer-1 angles]
//   e_0 = c1c2c3 t0t1t3 + c1c2s3 r0r1r3 + s1s2c3 t0r1r3 + s1s2s3 r0t1t3
//   e_1 = (c0c1 t0t2 + s0s1 r0r2) t3
//   e_2 = c0c1c2 t1t3 + c0s1s2 r1r3
//   e_3 = c0c1c2c3 t0t2 + s0s1c2c3 r0r2 + s0c1s2s3 t0r2 + c0s1s2s3 r0t2
// Verified vs direct statevector simulation in 7 hand cases incl. one that
// isolates the r-terms.  w_out/psi products folded into 12 per-lane weights.
// Layout (verified rounds 3-7): 32 lanes/element, lane = wire/gate w [1:0],
// unit j [4:2], element e [5]; 2 elements/wave, 512 blocks.

#define NQ 4
#define NL 2
#define BB 1024
#define TT 64
#define FF 32
#define HH 8

typedef unsigned uv2 __attribute__((ext_vector_type(2)));

// DPP quad_perm broadcast of quad position (VALU cross-lane)
#define QUAD_BCAST(x, CTRL) \
    __int_as_float(__builtin_amdgcn_mov_dpp(__float_as_int(x), (CTRL), 0xf, 0xf, true))
// DPP row rotate (within 16-lane row)
#define ROW_ROR(x, N) \
    __int_as_float(__builtin_amdgcn_mov_dpp(__float_as_int(x), 0x120 + (N), 0xf, 0xf, true))
// ds_swizzle lane ^ 16 (fallback)
#define SWZ_X16(x) \
    __int_as_float(__builtin_amdgcn_ds_swizzle(__float_as_int(x), 0x401F))

#if __has_builtin(__builtin_amdgcn_permlane16_swap)
__device__ __forceinline__ float permx16(float s, int lane) {
    uv2 r = __builtin_amdgcn_permlane16_swap(__builtin_bit_cast(unsigned, s),
                                             __builtin_bit_cast(unsigned, s),
                                             false, false);
    unsigned pick = (lane & 16) ? r.x : r.y;
    return __builtin_bit_cast(float, pick);
}
#else
__device__ __forceinline__ float permx16(float s, int lane) {
    (void)lane;
    return SWZ_X16(s);
}
#endif

#define XSTRIDE 68   // floats; 272B rows: 16B-aligned, 2-way bank aliasing only

__global__ __launch_bounds__(64, 1)
void qlstm_hb_kernel(const float* __restrict__ x,
                     const float* __restrict__ w_in,
                     const float* __restrict__ b_in,
                     const float* __restrict__ w_out,
                     const float* __restrict__ b_out,
                     const float* __restrict__ wq_f,
                     const float* __restrict__ wq_i,
                     const float* __restrict__ wq_u,
                     const float* __restrict__ wq_o,
                     const float* __restrict__ w_fc,
                     const float* __restrict__ b_fc,
                     float* __restrict__ out) {
    __shared__ __align__(16) float sXW[8 * XSTRIDE];   // [(e*4+w)][t]

    const int lane = threadIdx.x;
    const int w    = lane & 3;          // gate id AND wire id for this lane
    const int j    = (lane >> 2) & 7;   // hidden unit owned by this lane
    const int e    = lane >> 5;         // element slot (2 per block)

    // ---------------- P1: xw[(e,w)][t] = b_in[w] + x[elem,t,:].w_in[w,8:] ---
    {
        const float b0 = b_in[0], b1 = b_in[1], b2 = b_in[2], b3 = b_in[3];
        #pragma unroll
        for (int r = 0; r < 8; ++r) {
            int slot = lane + 64 * r;          // 0..511 = ee(1) t(6) w(2)
            int ee = slot >> 8;
            int tt = (slot >> 2) & 63;
            int ww = slot & 3;
            const float* xr = x + ((size_t)(blockIdx.x * 2 + ee) * TT + tt) * FF;
            float bb = (ww == 0) ? b0 : (ww == 1) ? b1 : (ww == 2) ? b2 : b3;
            const float* wrow = w_in + ww * 40 + 8;
            float acc0 = bb, acc1 = 0.0f;
            #pragma unroll
            for (int k = 0; k < 8; k += 2) {
                float4 xa = *reinterpret_cast<const float4*>(xr + 4 * k);
                float4 xb = *reinterpret_cast<const float4*>(xr + 4 * k + 4);
                acc0 = fmaf(xa.x, wrow[4*k+0],
                       fmaf(xa.y, wrow[4*k+1],
                       fmaf(xa.z, wrow[4*k+2],
                       fmaf(xa.w, wrow[4*k+3], acc0))));
                acc1 = fmaf(xb.x, wrow[4*k+4],
                       fmaf(xb.y, wrow[4*k+5],
                       fmaf(xb.z, wrow[4*k+6],
                       fmaf(xb.w, wrow[4*k+7], acc1))));
            }
            sXW[(ee * 4 + ww) * XSTRIDE + tt] = acc0 + acc1;
        }
    }
    __syncthreads();

    // ---------------- per-lane closed-form circuit constants ----------------
    const float* wq = (w == 0) ? wq_f : (w == 1) ? wq_i : (w == 2) ? wq_u : wq_o;
    // layer-0 angles phi -> (t,r) rotation coefficients
    const float cph0 = __cosf(wq[0]), sph0 = __sinf(wq[0]);
    const float cph1 = __cosf(wq[1]), sph1 = __sinf(wq[1]);
    const float cph2 = __cosf(wq[2]), sph2 = __sinf(wq[2]);
    const float cph3 = __cosf(wq[3]), sph3 = __sinf(wq[3]);
    // layer-1 angles psi
    const float c0 = __cosf(wq[4]), s0 = __sinf(wq[4]);
    const float c1 = __cosf(wq[5]), s1 = __sinf(wq[5]);
    const float c2 = __cosf(wq[6]), s2 = __sinf(wq[6]);
    const float c3 = __cosf(wq[7]), s3 = __sinf(wq[7]);
    // fold w_out row j and the psi-products into 12 weights
    const float wo0 = w_out[j * 4 + 0], wo1 = w_out[j * 4 + 1];
    const float wo2 = w_out[j * 4 + 2], wo3 = w_out[j * 4 + 3];
    const float g0a = wo0 * (c1 * c2 * c3);   // * t0 * P   (P = t1 t3)
    const float g0b = wo0 * (c1 * c2 * s3);   // * r0 * Q   (Q = r1 r3)
    const float g0c = wo0 * (s1 * s2 * c3);   // * t0 * Q
    const float g0d = wo0 * (s1 * s2 * s3);   // * r0 * P
    const float g1a = wo1 * (c0 * c1);        // * S * t3   (S = t0 t2)
    const float g1b = wo1 * (s0 * s1);        // * T * t3   (T = r0 r2)
    const float g2a = wo2 * (c0 * c1 * c2);   // * P
    const float g2b = wo2 * (c0 * s1 * s2);   // * Q
    const float g3a = wo3 * (c0 * c1 * c2 * c3);  // * S
    const float g3b = wo3 * (s0 * s1 * c2 * c3);  // * T
    const float g3c = wo3 * (s0 * c1 * s2 * s3);  // * U   (U = t0 r2)
    const float g3d = wo3 * (c0 * s1 * s2 * s3);  // * V   (V = r0 t2)
    const float bo  = b_out[j];

    const float wh  = w_in[w * 40 + j];
    const float wfc = w_fc[j];
    const bool  isG  = (w == 2);
    const float inS  = isG ? 2.0f : 1.0f;
    const float outS = isG ? 2.0f : 1.0f;
    const float outB = isG ? -1.0f : 0.0f;

    const float* sxw = sXW + (e * 4 + w) * XSTRIDE;

    float cc = 0.0f, hh = 0.0f;

#define STEP(xwv) do {                                                        \
    /* y_w = xw + sum_j w_in[w,j] h_j  (row-DPP + permlane^16, no DS) */      \
    float p_ = hh * wh;                                                       \
    float s_ = p_ + ROW_ROR(p_, 4);                                           \
    s_ = s_ + ROW_ROR(s_, 8);                                                 \
    const float y_ = (xwv) + s_ + permx16(s_, lane);                          \
    const float u_ = __cosf(y_), v_ = __sinf(y_);                             \
    const float u0_ = QUAD_BCAST(u_, 0x00), u1_ = QUAD_BCAST(u_, 0x55);       \
    const float u2_ = QUAD_BCAST(u_, 0xAA), u3_ = QUAD_BCAST(u_, 0xFF);       \
    const float v0_ = QUAD_BCAST(v_, 0x00), v1_ = QUAD_BCAST(v_, 0x55);       \
    const float v2_ = QUAD_BCAST(v_, 0xAA), v3_ = QUAD_BCAST(v_, 0xFF);       \
    /* t_q = cos(y_q+phi_q), r_q = sin(y_q+phi_q) for THIS lane's gate */     \
    const float t0_ = fmaf(cph0, u0_, -(sph0 * v0_));                         \
    const float t1_ = fmaf(cph1, u1_, -(sph1 * v1_));                         \
    const float t2_ = fmaf(cph2, u2_, -(sph2 * v2_));                         \
    const float t3_ = fmaf(cph3, u3_, -(sph3 * v3_));                         \
    const float r0_ = fmaf(sph0, u0_, cph0 * v0_);                            \
    const float r1_ = fmaf(sph1, u1_, cph1 * v1_);                            \
    const float r2_ = fmaf(sph2, u2_, cph2 * v2_);                            \
    const float r3_ = fmaf(sph3, u3_, cph3 * v3_);                            \
    /* pair products */                                                       \
    const float P_ = t1_ * t3_;                                               \
    const float Q_ = r1_ * r3_;                                               \
    const float S_ = t0_ * t2_;                                               \
    const float T_ = r0_ * r2_;                                               \
    const float U_ = t0_ * r2_;                                               \
    const float V_ = r0_ * t2_;                                               \
    /* 12-term pre-activation */                                              \
    const float mP_ = fmaf(g0a, t0_, fmaf(g0d, r0_, g2a));                    \
    const float mQ_ = fmaf(g0c, t0_, fmaf(g0b, r0_, g2b));                    \
    float a_ = fmaf(mP_, P_, fmaf(mQ_, Q_, bo));                              \
    const float e1_ = fmaf(g1a, S_, g1b * T_);                                \
    a_ = fmaf(e1_, t3_, a_);                                                  \
    a_ = fmaf(g3a, S_, a_);                                                   \
    a_ = fmaf(g3b, T_, a_);                                                   \
    a_ = fmaf(g3c, U_, a_);                                                   \
    a_ = fmaf(g3d, V_, a_);                                                   \
    /* activation (sigmoid; tanh = 2*sig(2a)-1 for gate u) */                 \
    const float sg_ = __builtin_amdgcn_rcpf(1.0f + __expf(-inS * a_));        \
    const float act_ = fmaf(sg_, outS, outB);                                 \
    const float fv_ = QUAD_BCAST(act_, 0x00), iv_ = QUAD_BCAST(act_, 0x55);   \
    const float gv_ = QUAD_BCAST(act_, 0xAA), ov_ = QUAD_BCAST(act_, 0xFF);   \
    cc = fmaf(fv_, cc, iv_ * gv_);                                            \
    const float th_ = fmaf(2.0f,                                              \
        __builtin_amdgcn_rcpf(1.0f + __expf(-2.0f * cc)), -1.0f);             \
    hh = ov_ * th_;                                                           \
} while (0)

    float4 xq = *reinterpret_cast<const float4*>(sxw);
    #pragma unroll 1
    for (int g4 = 0; g4 < 16; ++g4) {
        const int nx = (g4 < 15) ? (g4 + 1) * 4 : 60;   // clamp (discarded)
        float4 xqn = *reinterpret_cast<const float4*>(sxw + nx);
        STEP(xq.x);
        STEP(xq.y);
        STEP(xq.z);
        STEP(xq.w);
        xq = xqn;
    }
#undef STEP

    // ---------------- epilogue: out = h.w_fc + b_fc -------------------------
    float pf = hh * wfc;
    float sf = pf + ROW_ROR(pf, 4);
    sf = sf + ROW_ROR(sf, 8);
    sf = sf + permx16(sf, lane);
    if ((lane & 31) == 0) out[blockIdx.x * 2 + e] = sf + b_fc[0];
}

extern "C" void kernel_launch(void* const* d_in, const int* in_sizes, int n_in,
                              void* d_out, int out_size, void* d_ws, size_t ws_size,
                              hipStream_t stream) {
    const float* x     = (const float*)d_in[0];
    const float* w_in  = (const float*)d_in[1];
    const float* b_in  = (const float*)d_in[2];
    const float* w_out = (const float*)d_in[3];
    const float* b_out = (const float*)d_in[4];
    const float* wq_f  = (const float*)d_in[5];
    const float* wq_i  = (const float*)d_in[6];
    const float* wq_u  = (const float*)d_in[7];
    const float* wq_o  = (const float*)d_in[8];
    const float* w_fc  = (const float*)d_in[9];
    const float* b_fc  = (const float*)d_in[10];
    float* out = (float*)d_out;
    (void)in_sizes; (void)n_in; (void)out_size; (void)d_ws; (void)ws_size;

    qlstm_hb_kernel<<<BB / 2, 64, 0, stream>>>(x, w_in, b_in, w_out, b_out,
                                               wq_f, wq_i, wq_u, wq_o,
                                               w_fc, b_fc, out);
}